// Round 1
// baseline (135.605 us; speedup 1.0000x reference)
//
#include <hip/hip_runtime.h>

// x: (2048, 200, 11, 11) f32.  N = 2048*200*121 = 49,561,600 (divisible by 4).
// out[b,c,i,j] = exp( -(x[b,c,i,j]-x[b,c,5,5])^2 / S  -  (|i-5|+|j-5|)/2 )
// where S = sum over ALL elements of (x - per-plane-center)^2.

#define N_TOTAL   49561600
#define PLANE     121
#define CENTER_OFF 60          // 5*11 + 5
#define NBLOCKS   2048
#define NTHREADS  256

__global__ __launch_bounds__(NTHREADS) void fuzzy_reduce_kernel(
    const float* __restrict__ x, float* __restrict__ total)
{
    const int n4 = N_TOTAL / 4;
    float acc = 0.0f;
    for (int i4 = blockIdx.x * blockDim.x + threadIdx.x; i4 < n4;
         i4 += gridDim.x * blockDim.x) {
        float4 v = reinterpret_cast<const float4*>(x)[i4];
        float e[4] = {v.x, v.y, v.z, v.w};
        const int base = i4 * 4;
        #pragma unroll
        for (int j = 0; j < 4; ++j) {
            int idx   = base + j;
            int plane = idx / PLANE;                 // magic-mul (constant divisor)
            float cv  = x[plane * PLANE + CENTER_OFF];  // L1-broadcast hit
            float d   = e[j] - cv;
            acc += d * d;
        }
    }
    // wave (64-lane) shuffle reduction
    #pragma unroll
    for (int off = 32; off > 0; off >>= 1)
        acc += __shfl_down(acc, off, 64);

    __shared__ float wsum[NTHREADS / 64];
    const int lane = threadIdx.x & 63;
    const int wid  = threadIdx.x >> 6;
    if (lane == 0) wsum[wid] = acc;
    __syncthreads();
    if (threadIdx.x == 0) {
        float s = wsum[0] + wsum[1] + wsum[2] + wsum[3];
        atomicAdd(total, s);   // device-scope by default (cross-XCD safe)
    }
}

__global__ __launch_bounds__(NTHREADS) void fuzzy_finalize_kernel(
    const float* __restrict__ x, const float* __restrict__ total,
    float* __restrict__ out)
{
    __shared__ float dist_half[PLANE];
    if (threadIdx.x < PLANE) {
        int i = threadIdx.x / 11;
        int j = threadIdx.x % 11;
        float dist = fabsf((float)(i - 5)) + fabsf((float)(j - 5));
        dist_half[threadIdx.x] = dist * 0.5f;
    }
    __syncthreads();

    const float inv_total = 1.0f / (*total);   // cached scalar read

    const int n4 = N_TOTAL / 4;
    for (int i4 = blockIdx.x * blockDim.x + threadIdx.x; i4 < n4;
         i4 += gridDim.x * blockDim.x) {
        float4 v = reinterpret_cast<const float4*>(x)[i4];
        float e[4] = {v.x, v.y, v.z, v.w};
        float r[4];
        const int base = i4 * 4;
        #pragma unroll
        for (int j = 0; j < 4; ++j) {
            int idx    = base + j;
            int plane  = idx / PLANE;
            int within = idx - plane * PLANE;
            float cv   = x[plane * PLANE + CENTER_OFF];
            float d    = e[j] - cv;
            float arg  = -(d * d) * inv_total - dist_half[within];
            r[j] = __expf(arg);
        }
        float4 o = make_float4(r[0], r[1], r[2], r[3]);
        reinterpret_cast<float4*>(out)[i4] = o;
    }
}

extern "C" void kernel_launch(void* const* d_in, const int* in_sizes, int n_in,
                              void* d_out, int out_size, void* d_ws, size_t ws_size,
                              hipStream_t stream)
{
    const float* x   = (const float*)d_in[0];
    float*       out = (float*)d_out;
    float*       tot = (float*)d_ws;

    // zero the accumulator every call (d_ws is NOT re-poisoned between replays)
    hipMemsetAsync(tot, 0, sizeof(float), stream);

    fuzzy_reduce_kernel<<<NBLOCKS, NTHREADS, 0, stream>>>(x, tot);
    fuzzy_finalize_kernel<<<NBLOCKS, NTHREADS, 0, stream>>>(x, tot, out);
}

// Round 3
// 97.618 us; speedup vs baseline: 1.3891x; 1.3891x over previous
//
#include <hip/hip_runtime.h>

// x: (2048, 200, 11, 11) f32.  N = 2048*200*121 = 49,561,600 (divisible by 4).
// out[b,c,i,j] = exp( -(x[b,c,i,j]-x[b,c,5,5])^2 / S  -  (|i-5|+|j-5|)/2 )
// where S = sum over ALL elements of (x - per-plane-center)^2.
//
// Structure: 2 dispatches, no memset, no atomics.
//   K1: per-block partial sums of (x-center)^2 -> d_ws[bid]   (2048 floats)
//   K2: each block re-reduces the 2048 partials (cheap, amortized), then
//       streams x -> out with fused exp(-sq/S - dist/2).
//       Output stored nontemporal so the 198 MB write doesn't evict x from L3.

#define N_TOTAL    49561600
#define N4         (N_TOTAL / 4)     // 12,390,400
#define PLANE      121
#define CENTER_OFF 60                // 5*11 + 5
#define NBLOCKS    2048
#define NTHREADS   256

typedef float f32x4 __attribute__((ext_vector_type(4)));  // native vec for nt-store

__global__ __launch_bounds__(NTHREADS) void fuzzy_reduce_kernel(
    const float* __restrict__ x, float* __restrict__ partials)
{
    float acc = 0.0f;
    for (int i4 = blockIdx.x * NTHREADS + threadIdx.x; i4 < N4;
         i4 += NBLOCKS * NTHREADS) {
        f32x4 v = reinterpret_cast<const f32x4*>(x)[i4];
        const int base = i4 * 4;
        #pragma unroll
        for (int j = 0; j < 4; ++j) {
            int idx   = base + j;
            int plane = idx / PLANE;                    // magic-mul, const divisor
            float cv  = x[plane * PLANE + CENTER_OFF];  // L1 broadcast hit
            float d   = v[j] - cv;
            acc = fmaf(d, d, acc);
        }
    }
    // 64-lane shuffle reduce, then cross-wave via LDS
    #pragma unroll
    for (int off = 32; off > 0; off >>= 1)
        acc += __shfl_down(acc, off, 64);
    __shared__ float wsum[NTHREADS / 64];
    const int lane = threadIdx.x & 63;
    const int wid  = threadIdx.x >> 6;
    if (lane == 0) wsum[wid] = acc;
    __syncthreads();
    if (threadIdx.x == 0)
        partials[blockIdx.x] = wsum[0] + wsum[1] + wsum[2] + wsum[3];
}

__global__ __launch_bounds__(NTHREADS) void fuzzy_finalize_kernel(
    const float* __restrict__ x, const float* __restrict__ partials,
    float* __restrict__ out)
{
    // --- re-reduce the 2048 partials in every block (~8 loads/thread) ---
    float s = 0.0f;
    for (int i = threadIdx.x; i < NBLOCKS; i += NTHREADS)
        s += partials[i];
    #pragma unroll
    for (int off = 32; off > 0; off >>= 1)
        s += __shfl_down(s, off, 64);

    __shared__ float wsum[NTHREADS / 64];
    __shared__ float dist_half[PLANE];
    const int lane = threadIdx.x & 63;
    const int wid  = threadIdx.x >> 6;
    if (lane == 0) wsum[wid] = s;
    if (threadIdx.x < PLANE) {
        int i = threadIdx.x / 11;
        int j = threadIdx.x % 11;
        dist_half[threadIdx.x] =
            0.5f * (fabsf((float)(i - 5)) + fabsf((float)(j - 5)));
    }
    __syncthreads();
    const float inv_total = 1.0f / (wsum[0] + wsum[1] + wsum[2] + wsum[3]);

    // --- main stream: x (L3-resident after K1) -> out (nontemporal) ---
    for (int i4 = blockIdx.x * NTHREADS + threadIdx.x; i4 < N4;
         i4 += NBLOCKS * NTHREADS) {
        f32x4 v = reinterpret_cast<const f32x4*>(x)[i4];
        f32x4 r;
        const int base = i4 * 4;
        #pragma unroll
        for (int j = 0; j < 4; ++j) {
            int idx    = base + j;
            int plane  = idx / PLANE;
            int within = idx - plane * PLANE;
            float cv   = x[plane * PLANE + CENTER_OFF];
            float d    = v[j] - cv;
            r[j] = __expf(fmaf(-(d * d), inv_total, -dist_half[within]));
        }
        __builtin_nontemporal_store(r, reinterpret_cast<f32x4*>(out) + i4);
    }
}

extern "C" void kernel_launch(void* const* d_in, const int* in_sizes, int n_in,
                              void* d_out, int out_size, void* d_ws, size_t ws_size,
                              hipStream_t stream)
{
    const float* x        = (const float*)d_in[0];
    float*       out      = (float*)d_out;
    float*       partials = (float*)d_ws;   // 2048 floats, fully rewritten each call

    fuzzy_reduce_kernel<<<NBLOCKS, NTHREADS, 0, stream>>>(x, partials);
    fuzzy_finalize_kernel<<<NBLOCKS, NTHREADS, 0, stream>>>(x, partials, out);
}